// Round 1
// baseline (467.998 us; speedup 1.0000x reference)
//
#include <hip/hip_runtime.h>
#include <hip/hip_bf16.h>
#include <cstdint>
#include <cstddef>

typedef unsigned short ushort_t;
typedef __bf16 bf16x8v __attribute__((ext_vector_type(8)));
typedef float f32x4 __attribute__((ext_vector_type(4)));

#define BM 128
#define BN 128
#define BK 32

// Problem constants (from reference setup_inputs)
#define Bsz 4
#define Sseq 2048
#define Dd 1024
#define DFFd 4096
#define Ee 8
#define DFEd 1024
#define IDCUT 1024          // id = S//2
#define NTOK (Bsz*Sseq)     // 8192
#define NMOE (Bsz*(Sseq-IDCUT)) // 4096 MoE tokens
#define MAXSLOT 4096        // max slots per expert

__device__ __forceinline__ ushort_t f2bf(float f) {
  unsigned u = __float_as_uint(f);
  u += 0x7fffu + ((u >> 16) & 1u);       // round-to-nearest-even
  return (ushort_t)(u >> 16);
}

__device__ __forceinline__ float gelu_tanh(float x) {
  float x3 = x * x * x;
  float t = tanhf(0.7978845608028654f * (x + 0.044715f * x3));
  return 0.5f * x * (1.0f + t);
}

__device__ __forceinline__ void gload_lds16(const void* g, void* l) {
  __builtin_amdgcn_global_load_lds(
      (const __attribute__((address_space(1))) void*)g,
      (__attribute__((address_space(3))) void*)l,
      16, 0, 0);
}

// ---------------- cast x fp32 -> bf16 (straight) ----------------
__global__ void cast4_k(const float* __restrict__ in, ushort_t* __restrict__ out, int n4) {
  int i = blockIdx.x * 256 + threadIdx.x;
  if (i >= n4) return;
  const float4 v = ((const float4*)in)[i];
  ushort4 o;
  o.x = f2bf(v.x); o.y = f2bf(v.y); o.z = f2bf(v.z); o.w = f2bf(v.w);
  ((ushort4*)out)[i] = o;
}

// ---------------- transpose-cast: in [R][C] fp32 -> out [C][R] bf16, batched over z ----------------
__global__ void tcast_k(const float* __restrict__ in, ushort_t* __restrict__ out, int R, int C) {
  __shared__ float tile[32][33];
  const size_t base = (size_t)blockIdx.z * (size_t)R * (size_t)C;
  in += base; out += base;
  int tx = threadIdx.x & 31, ty = threadIdx.x >> 5;   // 32 x 8
  int c = blockIdx.x * 32 + tx;
  #pragma unroll
  for (int i = 0; i < 32; i += 8) {
    int r = blockIdx.y * 32 + ty + i;
    tile[ty + i][tx] = in[(size_t)r * C + c];
  }
  __syncthreads();
  int rr = blockIdx.y * 32 + tx;
  #pragma unroll
  for (int i = 0; i < 32; i += 8) {
    int cc = blockIdx.x * 32 + ty + i;
    out[(size_t)cc * R + rr] = f2bf(tile[tx][ty + i]);
  }
}

// ---------------- router: top-2 gates + per-expert slot lists ----------------
__global__ void router_k(const float* __restrict__ x, const float* __restrict__ Wg,
                         int* __restrict__ cnt, int* __restrict__ slots,
                         float* __restrict__ gsv) {
  int t = blockIdx.x * 4 + (threadIdx.x >> 6);   // one wave per MoE token
  int lane = threadIdx.x & 63;
  int b = t >> 10;
  int s = (t & 1023) + IDCUT;
  const float* xr = x + ((size_t)b * Sseq + s) * Dd;
  float acc[8] = {0.f,0.f,0.f,0.f,0.f,0.f,0.f,0.f};
  for (int k = lane; k < Dd; k += 64) {
    float xv = xr[k];
    const float* wr = Wg + (size_t)k * Ee;
    #pragma unroll
    for (int e8 = 0; e8 < 8; ++e8) acc[e8] += xv * wr[e8];
  }
  #pragma unroll
  for (int off = 32; off > 0; off >>= 1) {
    #pragma unroll
    for (int e8 = 0; e8 < 8; ++e8) acc[e8] += __shfl_xor(acc[e8], off);
  }
  if (lane == 0) {
    int e0 = 0; float v0 = acc[0];
    #pragma unroll
    for (int e8 = 1; e8 < 8; ++e8) if (acc[e8] > v0) { v0 = acc[e8]; e0 = e8; }
    int e1 = -1; float v1 = -3.4e38f;
    #pragma unroll
    for (int e8 = 0; e8 < 8; ++e8) if (e8 != e0 && acc[e8] > v1) { v1 = acc[e8]; e1 = e8; }
    float g0 = 1.0f / (1.0f + expf(v1 - v0));   // = p0/(p0+p1), exact through softmax monotonicity
    float g1 = 1.0f - g0;
    int p0 = atomicAdd(&cnt[e0], 1);
    slots[e0 * MAXSLOT + p0] = t * 2;
    int p1 = atomicAdd(&cnt[e1], 1);
    slots[e1 * MAXSLOT + p1] = t * 2 + 1;
    gsv[t * 2] = g0;
    gsv[t * 2 + 1] = g1;
  }
}

// ---------------- GEMM: C[M,N] = A[M,K] * Bt[N,K]^T  (m97 128x128xBK32 structure) ----------------
// MODE 0: FFN1  A=xb direct,     epi: gelu(acc+b1)      -> bf16 h1
// MODE 1: FFN2  A=h1 direct,     epi: acc+b2            -> fp32 out
// MODE 2: MoE1  A=xb gathered,   epi: gelu(acc+be1[e])  -> bf16 h_slot[sv]
// MODE 3: MoE2  A=h_slot gather, epi: gate*(acc+be2[e]) -> fp32 eo[sv]
template<int MODE>
__global__ __launch_bounds__(256, 2) void gemm_k(
    const ushort_t* __restrict__ A,
    const ushort_t* __restrict__ Bt,
    const float* __restrict__ bias,
    void* __restrict__ C,
    int M, int K, int lda, int ldc,
    const int* __restrict__ cnt,
    const int* __restrict__ slots,
    const float* __restrict__ gates)
{
  const int nt = blockIdx.x, mt = blockIdx.y, e = blockIdx.z;
  int rows = M;
  const int* slist = nullptr;
  if (MODE >= 2) {
    rows = cnt[e];
    if (mt * BM >= rows) return;
    slist = slots + e * MAXSLOT;
  }
  const ushort_t* Bte = (MODE >= 2) ? (Bt + (size_t)e * (size_t)K * 1024u) : Bt;
  const float* biase = (MODE >= 2) ? (bias + e * 1024) : bias;

  __shared__ ushort_t Al[BM * BK];
  __shared__ ushort_t Bl[BN * BK];

  const int tid = threadIdx.x;
  const int lane = tid & 63;
  const int wid = tid >> 6;
  const int wr = wid >> 1, wc = wid & 1;

  // --- staging address setup: 8 wave-groups of 16 rows x 64B ---
  const int srow = lane >> 2;          // row within 16-row group
  const int kofs = (lane & 3) * 8;     // element offset within row (16B granules)

  const ushort_t* gA[2];
  const ushort_t* gB[2];
  ushort_t* lA[2];
  ushort_t* lB[2];
  #pragma unroll
  for (int j = 0; j < 2; ++j) {
    int rgrp = (j * 4 + wid) * 16;
    int arow = mt * BM + rgrp + srow;
    size_t asrc;
    if (MODE < 2) {
      asrc = (size_t)arow * (size_t)lda;
    } else {
      int idx = arow; if (idx > rows - 1) idx = rows - 1;
      int sv = slist[idx];
      size_t gr;
      if (MODE == 2) {
        int t = sv >> 1;
        gr = (size_t)((t >> 10) * Sseq + IDCUT + (t & 1023));
      } else {
        gr = (size_t)sv;
      }
      asrc = gr * (size_t)lda;
    }
    gA[j] = A + asrc + kofs;
    lA[j] = &Al[(j * 4 + wid) * 512];
    int brow = nt * BN + rgrp + srow;
    gB[j] = Bte + (size_t)brow * (size_t)K + kofs;
    lB[j] = &Bl[(j * 4 + wid) * 512];
  }

  f32x4 acc[4][4];
  const f32x4 vzero = {0.f, 0.f, 0.f, 0.f};
  #pragma unroll
  for (int m = 0; m < 4; ++m)
    #pragma unroll
    for (int n = 0; n < 4; ++n) acc[m][n] = vzero;

  const int lr = lane & 15;
  const int qr = lane >> 4;
  const ushort_t* aBase = &Al[(wr * 64 + lr) * BK + qr * 8];
  const ushort_t* bBase = &Bl[(wc * 64 + lr) * BK + qr * 8];

  for (int k0 = 0; k0 < K; k0 += BK) {
    __syncthreads();
    #pragma unroll
    for (int j = 0; j < 2; ++j) {
      gload_lds16(gA[j] + k0, lA[j]);
      gload_lds16(gB[j] + k0, lB[j]);
    }
    __syncthreads();

    bf16x8v af[4], bfr[4];
    #pragma unroll
    for (int m = 0; m < 4; ++m) af[m] = *(const bf16x8v*)(aBase + m * 16 * BK);
    #pragma unroll
    for (int n = 0; n < 4; ++n) bfr[n] = *(const bf16x8v*)(bBase + n * 16 * BK);
    #pragma unroll
    for (int m = 0; m < 4; ++m)
      #pragma unroll
      for (int n = 0; n < 4; ++n)
        acc[m][n] = __builtin_amdgcn_mfma_f32_16x16x32_bf16(af[m], bfr[n], acc[m][n], 0, 0, 0);
  }

  // --- epilogue: C/D layout col = lane&15, row = (lane>>4)*4 + j ---
  #pragma unroll
  for (int m = 0; m < 4; ++m) {
    #pragma unroll
    for (int j = 0; j < 4; ++j) {
      int lrow = wr * 64 + m * 16 + qr * 4 + j;
      int grow = mt * BM + lrow;
      size_t crow;
      float gt = 0.f;
      if (MODE >= 2) {
        if (grow >= rows) continue;
        int sv = slist[grow];
        crow = (size_t)sv;
        if (MODE == 3) gt = gates[sv];
      } else {
        crow = (size_t)grow;
      }
      #pragma unroll
      for (int n = 0; n < 4; ++n) {
        int gcol = nt * BN + wc * 64 + n * 16 + lr;
        float v = acc[m][n][j] + biase[gcol];
        if (MODE == 0 || MODE == 2) {
          ((ushort_t*)C)[crow * (size_t)ldc + gcol] = f2bf(gelu_tanh(v));
        } else if (MODE == 1) {
          ((float*)C)[crow * (size_t)ldc + gcol] = v;
        } else {
          ((float*)C)[crow * (size_t)ldc + gcol] = gt * v;
        }
      }
    }
  }
}

// ---------------- combine: out[moe rows] += LAM*(eo[2t] + eo[2t+1]) ----------------
__global__ void combine_k(float* __restrict__ out, const float* __restrict__ eo) {
  int i = blockIdx.x * 256 + threadIdx.x;    // over NMOE*1024/4 float4s
  int t = i >> 8;                            // 256 float4 per row
  int c4 = i & 255;
  size_t r = (size_t)((t >> 10) * Sseq + IDCUT + (t & 1023));
  const float4 a = ((const float4*)(eo + (size_t)(2 * t) * Dd))[c4];
  const float4 b = ((const float4*)(eo + (size_t)(2 * t + 1) * Dd))[c4];
  float4* op = (float4*)(out + r * Dd);
  float4 o = op[c4];
  o.x += 0.5f * (a.x + b.x);
  o.y += 0.5f * (a.y + b.y);
  o.z += 0.5f * (a.z + b.z);
  o.w += 0.5f * (a.w + b.w);
  op[c4] = o;
}

// ---------------- workspace layout (bytes) ----------------
#define WS_XB    ((size_t)0)           // 16777216   xb bf16 [8192][1024]
#define WS_W1T   ((size_t)16777216)    //  8388608   W1^T bf16 [4096][1024]
#define WS_W2T   ((size_t)25165824)    //  8388608   W2^T bf16 [1024][4096]
#define WS_WE1T  ((size_t)33554432)    // 16777216   We1^T bf16 [8][1024][1024]
#define WS_WE2T  ((size_t)50331648)    // 16777216   We2^T bf16 [8][1024][1024]
#define WS_H1    ((size_t)67108864)    // 67108864   h1 bf16 [8192][4096]
#define WS_HS    ((size_t)134217728)   // 16777216   h_slot bf16 [8192][1024]
#define WS_EO    ((size_t)150994944)   // 33554432   eo fp32 [8192][1024]
#define WS_CNT   ((size_t)184549376)   // 256        cnt int[8]
#define WS_SLOT  ((size_t)184549632)   // 131072     slots int[8][4096]
#define WS_GSV   ((size_t)184680704)   // 32768      gate per slot fp32[8192]

extern "C" void kernel_launch(void* const* d_in, const int* in_sizes, int n_in,
                              void* d_out, int out_size, void* d_ws, size_t ws_size,
                              hipStream_t stream) {
  const float* x   = (const float*)d_in[0];
  const float* W1  = (const float*)d_in[1];
  const float* b1  = (const float*)d_in[2];
  const float* W2  = (const float*)d_in[3];
  const float* b2  = (const float*)d_in[4];
  const float* Wg  = (const float*)d_in[5];
  const float* We1 = (const float*)d_in[6];
  const float* be1 = (const float*)d_in[7];
  const float* We2 = (const float*)d_in[8];
  const float* be2 = (const float*)d_in[9];
  float* out = (float*)d_out;

  char* ws = (char*)d_ws;
  ushort_t* xb   = (ushort_t*)(ws + WS_XB);
  ushort_t* W1t  = (ushort_t*)(ws + WS_W1T);
  ushort_t* W2t  = (ushort_t*)(ws + WS_W2T);
  ushort_t* We1t = (ushort_t*)(ws + WS_WE1T);
  ushort_t* We2t = (ushort_t*)(ws + WS_WE2T);
  ushort_t* h1   = (ushort_t*)(ws + WS_H1);
  ushort_t* hs   = (ushort_t*)(ws + WS_HS);
  float*    eo   = (float*)(ws + WS_EO);
  int*      cnt  = (int*)(ws + WS_CNT);
  int*      slots= (int*)(ws + WS_SLOT);
  float*    gsv  = (float*)(ws + WS_GSV);

  hipMemsetAsync(cnt, 0, 8 * sizeof(int), stream);

  // casts / transposes
  cast4_k<<<NTOK * Dd / 4 / 256, 256, 0, stream>>>(x, xb, NTOK * Dd / 4);
  tcast_k<<<dim3(DFFd / 32, Dd / 32, 1), 256, 0, stream>>>(W1, W1t, Dd, DFFd);
  tcast_k<<<dim3(Dd / 32, DFFd / 32, 1), 256, 0, stream>>>(W2, W2t, DFFd, Dd);
  tcast_k<<<dim3(DFEd / 32, Dd / 32, Ee), 256, 0, stream>>>(We1, We1t, Dd, DFEd);
  tcast_k<<<dim3(Dd / 32, DFEd / 32, Ee), 256, 0, stream>>>(We2, We2t, DFEd, Dd);

  // router
  router_k<<<NMOE / 4, 256, 0, stream>>>(x, Wg, cnt, slots, gsv);

  // FFN1: h1 = gelu(xb @ W1 + b1)    M=8192 N=4096 K=1024
  gemm_k<0><<<dim3(DFFd / BN, NTOK / BM, 1), 256, 0, stream>>>(
      xb, W1t, b1, h1, NTOK, Dd, Dd, DFFd, nullptr, nullptr, nullptr);
  // MoE1: h_slot = gelu(gather(xb) @ We1[e] + be1[e])
  gemm_k<2><<<dim3(DFEd / BN, MAXSLOT / BM, Ee), 256, 0, stream>>>(
      xb, We1t, be1, hs, 0, Dd, Dd, DFEd, cnt, slots, gsv);
  // FFN2: out = h1 @ W2 + b2         M=8192 N=1024 K=4096
  gemm_k<1><<<dim3(Dd / BN, NTOK / BM, 1), 256, 0, stream>>>(
      h1, W2t, b2, out, NTOK, DFFd, DFFd, Dd, nullptr, nullptr, nullptr);
  // MoE2: eo = gate * (h_slot @ We2[e] + be2[e])
  gemm_k<3><<<dim3(Dd / BN, MAXSLOT / BM, Ee), 256, 0, stream>>>(
      hs, We2t, be2, eo, 0, DFEd, DFEd, Dd, cnt, slots, gsv);
  // combine
  combine_k<<<NMOE * Dd / 4 / 256, 256, 0, stream>>>(out, eo);
}